// Round 11
// baseline (480.270 us; speedup 1.0000x reference)
//
#include <hip/hip_runtime.h>
#include <hip/hip_fp16.h>

#define HEADS 2
#define DD 128
#define FF 16
#define HD 256  // HEADS*DD
#define NEG_SLOPE 0.2f
#define EPSV 1e-16f

static __device__ __forceinline__ float rdlanef(float v, int i){
  return __uint_as_float(__builtin_amdgcn_readlane(__float_as_uint(v), i));
}
static __device__ __forceinline__ int rdlanei(int v, int i){
  return __builtin_amdgcn_readlane(v, i);
}
static __device__ __forceinline__ float4 h4f(uint2 u){
  __half2 h0 = *(__half2*)&u.x;
  __half2 h1 = *(__half2*)&u.y;
  float2 f0 = __half22float2(h0);
  float2 f1 = __half22float2(h1);
  return make_float4(f0.x, f0.y, f1.x, f1.y);
}

// ---------------- CSR build ----------------
// blocks [0, ebl): histogram of dst. blocks [ebl, ebl+5): per-layer attr-projection constants.
__global__ void k_hist_prec(const int* __restrict__ dst, int* __restrict__ counts,
                            const float* __restrict__ atts, const float* __restrict__ edge_ws,
                            const float* __restrict__ edge_bs, float* __restrict__ c5,
                            int E, int Etot, int ebl){
  if ((int)blockIdx.x >= ebl){
    int l = blockIdx.x - ebl;
    int t = threadIdx.x;
    const float* att = atts    + (size_t)l*HEADS*2*DD;
    const float* ew  = edge_ws + (size_t)l*HD*FF;
    const float* eb  = edge_bs + (size_t)l*HD;
    float* c = c5 + (size_t)l*34;
    if (t < 32){
      int h = t >> 4, f = t & 15;
      float acc = 0.f;
      for (int d = 0; d < DD; d++) acc += att[h*2*DD + DD + d]*ew[(size_t)(h*DD+d)*FF + f];
      c[h*FF + f] = acc;
    } else if (t < 34){
      int h = t - 32;
      float acc = 0.f;
      for (int d = 0; d < DD; d++) acc += att[h*2*DD + DD + d]*eb[h*DD + d];
      c[32 + h] = acc;
    }
    return;
  }
  int e = blockIdx.x*256 + threadIdx.x;
  if (e >= Etot) return;
  int dn = (e < E) ? dst[e] : (e - E);
  atomicAdd(&counts[dn], 1);
}

__global__ __launch_bounds__(1024) void k_scan(const int* __restrict__ counts, int* __restrict__ starts,
                       int* __restrict__ cursor, int N, int Etot){
  __shared__ int s[1024];
  int t = threadIdx.x;
  const int CHN = (N + 1023) / 1024;
  int lo = t*CHN, hi = min(lo+CHN, N);
  int loc = 0;
  for (int i = lo; i < hi; i++) loc += counts[i];
  s[t] = loc;
  __syncthreads();
  for (int off = 1; off < 1024; off <<= 1){
    int v = (t >= off) ? s[t-off] : 0;
    __syncthreads();
    s[t] += v;
    __syncthreads();
  }
  int run = (t == 0) ? 0 : s[t-1];
  for (int i = lo; i < hi; i++){
    starts[i] = run; cursor[i] = run; run += counts[i];
  }
  if (t == 0) starts[N] = Etot;
}

// scatter into CSR order: srcC + fp16 attr only (attrdot moved to coalesced pass)
__global__ void k_scatter(const int* __restrict__ dst, const int* __restrict__ src,
                          const float* __restrict__ eattr, int* __restrict__ cursor,
                          int* __restrict__ srcC, __half* __restrict__ attrC16,
                          int E, int Etot){
  int e = blockIdx.x*256 + threadIdx.x;
  if (e >= Etot) return;
  int dn, sn;
  float a[FF];
  if (e < E){
    dn = dst[e]; sn = src[e];
    const float4* in = (const float4*)&eattr[(size_t)e*FF];
    float4 q0=in[0], q1=in[1], q2=in[2], q3=in[3];
    a[0]=q0.x; a[1]=q0.y; a[2]=q0.z; a[3]=q0.w;
    a[4]=q1.x; a[5]=q1.y; a[6]=q1.z; a[7]=q1.w;
    a[8]=q2.x; a[9]=q2.y; a[10]=q2.z; a[11]=q2.w;
    a[12]=q3.x; a[13]=q3.y; a[14]=q3.z; a[15]=q3.w;
  } else {
    dn = sn = e - E;
    #pragma unroll
    for (int f = 0; f < FF; f++) a[f] = 0.f;
  }
  int pos = atomicAdd(&cursor[dn], 1);
  srcC[pos] = sn;
  uint4 pk0, pk1;
  {
    __half2 h0 = __floats2half2_rn(a[0],a[1]),  h1 = __floats2half2_rn(a[2],a[3]);
    __half2 h2 = __floats2half2_rn(a[4],a[5]),  h3 = __floats2half2_rn(a[6],a[7]);
    __half2 h4 = __floats2half2_rn(a[8],a[9]),  h5 = __floats2half2_rn(a[10],a[11]);
    __half2 h6 = __floats2half2_rn(a[12],a[13]),h7 = __floats2half2_rn(a[14],a[15]);
    pk0.x=*(unsigned*)&h0; pk0.y=*(unsigned*)&h1; pk0.z=*(unsigned*)&h2; pk0.w=*(unsigned*)&h3;
    pk1.x=*(unsigned*)&h4; pk1.y=*(unsigned*)&h5; pk1.z=*(unsigned*)&h6; pk1.w=*(unsigned*)&h7;
  }
  uint4* ob = (uint4*)&attrC16[(size_t)pos*FF];
  ob[0] = pk0; ob[1] = pk1;
}

// coalesced pass: attrdot[l][i][2] = attrC16[i] . c5[l]
__global__ void k_attrdot(const __half* __restrict__ attrC16, const float* __restrict__ c5,
                          float* __restrict__ attrdot, int Etot){
  int i = blockIdx.x*256 + threadIdx.x;
  if (i >= Etot) return;
  const uint4* ap = (const uint4*)&attrC16[(size_t)i*FF];
  uint4 p0 = ap[0], p1 = ap[1];
  float a[FF];
  {
    float2 f;
    f = __half22float2(*(__half2*)&p0.x); a[0]=f.x;  a[1]=f.y;
    f = __half22float2(*(__half2*)&p0.y); a[2]=f.x;  a[3]=f.y;
    f = __half22float2(*(__half2*)&p0.z); a[4]=f.x;  a[5]=f.y;
    f = __half22float2(*(__half2*)&p0.w); a[6]=f.x;  a[7]=f.y;
    f = __half22float2(*(__half2*)&p1.x); a[8]=f.x;  a[9]=f.y;
    f = __half22float2(*(__half2*)&p1.y); a[10]=f.x; a[11]=f.y;
    f = __half22float2(*(__half2*)&p1.z); a[12]=f.x; a[13]=f.y;
    f = __half22float2(*(__half2*)&p1.w); a[14]=f.x; a[15]=f.y;
  }
  #pragma unroll
  for (int l = 0; l < 5; l++){
    const float* cl = c5 + (size_t)l*34;
    float d0 = 0.f, d1 = 0.f;
    #pragma unroll
    for (int f = 0; f < FF; f++){
      d0 = fmaf(a[f], cl[f], d0);
      d1 = fmaf(a[f], cl[FF+f], d1);
    }
    *(float2*)&attrdot[((size_t)l*Etot + i)*2] = make_float2(d0, d1);
  }
}

// xw[N,256] (fp16) = h[N,128] @ W[128,256]; fused s[n][4] = {si_h0, si_h1, sj_h0, sj_h1}
__global__ __launch_bounds__(256) void k_gemm_xw(const float* __restrict__ h, const float* __restrict__ W,
                         const float* __restrict__ att, __half* __restrict__ xwh,
                         float* __restrict__ sbuf, int N){
  __shared__ float sx[32][DD];
  int r0 = blockIdx.x * 32;
  int rows = min(32, N - r0);
  int t = threadIdx.x;
  for (int idx = t; idx < 32*(DD/4); idx += 256){
    int r = idx >> 5, kq = idx & 31;
    float4 v = make_float4(0.f,0.f,0.f,0.f);
    if (r < rows) v = *(const float4*)&h[(size_t)(r0+r)*DD + kq*4];
    *(float4*)&sx[r][kq*4] = v;
  }
  __syncthreads();
  int tx = t & 63, ty = t >> 6;
  int c0 = tx*4;
  float4 acc[8];
  #pragma unroll
  for (int r = 0; r < 8; r++) acc[r] = make_float4(0.f,0.f,0.f,0.f);
  #pragma unroll 8
  for (int kq = 0; kq < 32; kq++){
    float4 w0 = *(const float4*)&W[(size_t)(kq*4+0)*HD + c0];
    float4 w1 = *(const float4*)&W[(size_t)(kq*4+1)*HD + c0];
    float4 w2 = *(const float4*)&W[(size_t)(kq*4+2)*HD + c0];
    float4 w3 = *(const float4*)&W[(size_t)(kq*4+3)*HD + c0];
    #pragma unroll
    for (int r = 0; r < 8; r++){
      float4 hv = *(const float4*)&sx[ty*8+r][kq*4];
      acc[r].x = fmaf(hv.x, w0.x, acc[r].x); acc[r].y = fmaf(hv.x, w0.y, acc[r].y);
      acc[r].z = fmaf(hv.x, w0.z, acc[r].z); acc[r].w = fmaf(hv.x, w0.w, acc[r].w);
      acc[r].x = fmaf(hv.y, w1.x, acc[r].x); acc[r].y = fmaf(hv.y, w1.y, acc[r].y);
      acc[r].z = fmaf(hv.y, w1.z, acc[r].z); acc[r].w = fmaf(hv.y, w1.w, acc[r].w);
      acc[r].x = fmaf(hv.z, w2.x, acc[r].x); acc[r].y = fmaf(hv.z, w2.y, acc[r].y);
      acc[r].z = fmaf(hv.z, w2.z, acc[r].z); acc[r].w = fmaf(hv.z, w2.w, acc[r].w);
      acc[r].x = fmaf(hv.w, w3.x, acc[r].x); acc[r].y = fmaf(hv.w, w3.y, acc[r].y);
      acc[r].z = fmaf(hv.w, w3.z, acc[r].z); acc[r].w = fmaf(hv.w, w3.w, acc[r].w);
    }
  }
  #pragma unroll
  for (int r = 0; r < 8; r++){
    if (ty*8+r < rows){
      __half2 p0 = __floats2half2_rn(acc[r].x, acc[r].y);
      __half2 p1 = __floats2half2_rn(acc[r].z, acc[r].w);
      uint2 pk;
      pk.x = *(unsigned*)&p0;
      pk.y = *(unsigned*)&p1;
      *(uint2*)&xwh[(size_t)(r0+ty*8+r)*HD + c0] = pk;
    }
  }
  int hsel = tx >> 5;
  int cm = c0 & 127;
  float4 ai = *(const float4*)&att[hsel*2*DD + cm];
  float4 aj = *(const float4*)&att[hsel*2*DD + DD + cm];
  #pragma unroll
  for (int r = 0; r < 8; r++){
    float pi = acc[r].x*ai.x + acc[r].y*ai.y + acc[r].z*ai.z + acc[r].w*ai.w;
    float pj = acc[r].x*aj.x + acc[r].y*aj.y + acc[r].z*aj.z + acc[r].w*aj.w;
    #pragma unroll
    for (int off = 16; off; off >>= 1){
      pi += __shfl_xor(pi, off);
      pj += __shfl_xor(pj, off);
    }
    int row = ty*8 + r;
    if ((tx & 31) == 0 && row < rows){
      sbuf[(size_t)(r0+row)*4 + 0 + hsel] = pi;
      sbuf[(size_t)(r0+row)*4 + 2 + hsel] = pj;
    }
  }
}

// 4 waves per node (block = 1 node): wave wv handles edges st + 4k + wv.
// 40k waves (5x machine wave capacity) -> latency hidden by TLP instead of
// fighting the compiler for per-wave MLP (R8/R10 lesson). Partials merged in LDS.
#define BB 8
__global__ __launch_bounds__(256) void k_aggr(const int* __restrict__ starts, const int* __restrict__ srcC,
                      const __half* __restrict__ attrC16, const float* __restrict__ adL,
                      const float* __restrict__ s, const float* __restrict__ c,
                      const __half* __restrict__ xwh, const float* __restrict__ ew,
                      const float* __restrict__ eb, const float* __restrict__ bias,
                      float* __restrict__ out, int N, int relu){
  int lane = threadIdx.x & 63, wv = threadIdx.x >> 6;
  int n = blockIdx.x;

  float c32 = c[32], c33 = c[33];
  float sdx = s[(size_t)n*4+0], sdy = s[(size_t)n*4+1];
  int st = starts[n];
  int deg = starts[n+1] - st;
  int cw = (deg - wv + 3) >> 2;   // this wave's edge count (edge idx = st + 4k + wv)

  int f2 = lane & 15;
  int h2 = (lane >> 4) & 1;
  int hq = lane >> 5;
  const __half* xbase = xwh + lane*4;                       // lane's 4-col slice
  const __half* abase = attrC16 + (size_t)st*FF + wv*FF + f2; // + k*64

  float aAx=0.f, aAy=0.f, aAz=0.f, aAw=0.f;
  float aBx=0.f, aBy=0.f, aBz=0.f, aBw=0.f;
  float ls0=0.f, ls1=0.f, taccA=0.f, taccB=0.f;

  for (int base = 0; base < cw; base += 64){
    int cnt = min(64, cw - base);
    float e0 = 0.f, e1 = 0.f; int msrc = 0;
    if (lane < cnt){
      int idx = st + (base + lane)*4 + wv;
      msrc = srcC[idx];
      float2 sj = *(const float2*)&s[(size_t)msrc*4+2];
      float2 ad = *(const float2*)&adL[(size_t)idx*2];
      float x0 = sdx + sj.x + c32 + ad.x;
      float x1 = sdy + sj.y + c33 + ad.y;
      x0 = (x0 > 0.f) ? x0 : NEG_SLOPE*x0;
      x1 = (x1 > 0.f) ? x1 : NEG_SLOPE*x1;
      e0 = expf(x0); e1 = expf(x1);
      ls0 += e0; ls1 += e1;
    }
    int i = 0;
    for (; i + BB <= cnt; i += BB){
      uint2 u[BB];
      float av[BB];
      #pragma unroll
      for (int k = 0; k < BB; k++){
        int sn = rdlanei(msrc, i+k);
        u[k] = *(const uint2*)(xbase + (size_t)sn*HD);
      }
      #pragma unroll
      for (int k = 0; k < BB; k++) av[k] = __half2float(abase[(size_t)(base+i+k)*64]);
      #pragma unroll
      for (int k = 0; k < BB; k++){
        float w0 = rdlanef(e0, i+k);
        float w1 = rdlanef(e1, i+k);
        float ws = hq ? w1 : w0;
        float wt = h2 ? w1 : w0;
        float4 xv = h4f(u[k]);
        if (k & 1){
          aBx = fmaf(ws, xv.x, aBx); aBy = fmaf(ws, xv.y, aBy);
          aBz = fmaf(ws, xv.z, aBz); aBw = fmaf(ws, xv.w, aBw);
          taccB = fmaf(wt, av[k], taccB);
        } else {
          aAx = fmaf(ws, xv.x, aAx); aAy = fmaf(ws, xv.y, aAy);
          aAz = fmaf(ws, xv.z, aAz); aAw = fmaf(ws, xv.w, aAw);
          taccA = fmaf(wt, av[k], taccA);
        }
      }
    }
    for (; i < cnt; i++){
      int sn = rdlanei(msrc, i);
      float w0 = rdlanef(e0, i);
      float w1 = rdlanef(e1, i);
      uint2 u0 = *(const uint2*)(xbase + (size_t)sn*HD);
      float av0 = __half2float(abase[(size_t)(base+i)*64]);
      float ws = hq ? w1 : w0;
      float wt = h2 ? w1 : w0;
      float4 xv = h4f(u0);
      aAx = fmaf(ws, xv.x, aAx); aAy = fmaf(ws, xv.y, aAy);
      aAz = fmaf(ws, xv.z, aAz); aAw = fmaf(ws, xv.w, aAw);
      taccA = fmaf(wt, av0, taccA);
    }
  }
  float ax = aAx + aBx, ay = aAy + aBy, az = aAz + aBz, aw = aAw + aBw;
  float tacc = taccA + taccB;
  #pragma unroll
  for (int off = 32; off; off >>= 1){
    ls0 += __shfl_xor(ls0, off);
    ls1 += __shfl_xor(ls1, off);
  }

  // merge wave partials in LDS (waves 1..3 write, wave 0 reduces + epilogue)
  __shared__ float m_acc[3][4][64];
  __shared__ float m_t[3][64];
  __shared__ float m_ls[3][2];
  if (wv > 0){
    m_acc[wv-1][0][lane] = ax;
    m_acc[wv-1][1][lane] = ay;
    m_acc[wv-1][2][lane] = az;
    m_acc[wv-1][3][lane] = aw;
    m_t[wv-1][lane] = tacc;
    if (lane == 0){ m_ls[wv-1][0] = ls0; m_ls[wv-1][1] = ls1; }
  }
  __syncthreads();
  if (wv != 0) return;
  #pragma unroll
  for (int q = 0; q < 3; q++){
    ax += m_acc[q][0][lane];
    ay += m_acc[q][1][lane];
    az += m_acc[q][2][lane];
    aw += m_acc[q][3][lane];
    tacc += m_t[q][lane];
  }
  ls0 += m_ls[0][0] + m_ls[1][0] + m_ls[2][0];
  ls1 += m_ls[0][1] + m_ls[1][1] + m_ls[2][1];

  // epilogue: factored edge-emb + normalize + head-mean + bias (wave 0 only)
  int c0 = lane*4;
  float th[FF];
  #pragma unroll
  for (int f = 0; f < FF; f++) th[f] = __shfl(tacc, hq*FF + f);
  float embq[4];
  #pragma unroll
  for (int q = 0; q < 4; q++){
    const float4* er = (const float4*)&ew[(size_t)(c0+q)*FF];
    float4 g0 = er[0], g1 = er[1], g2 = er[2], g3 = er[3];
    float v = th[0]*g0.x + th[1]*g0.y + th[2]*g0.z + th[3]*g0.w;
    v = fmaf(th[4],  g1.x, v); v = fmaf(th[5],  g1.y, v); v = fmaf(th[6],  g1.z, v); v = fmaf(th[7],  g1.w, v);
    v = fmaf(th[8],  g2.x, v); v = fmaf(th[9],  g2.y, v); v = fmaf(th[10], g2.z, v); v = fmaf(th[11], g2.w, v);
    v = fmaf(th[12], g3.x, v); v = fmaf(th[13], g3.y, v); v = fmaf(th[14], g3.z, v); v = fmaf(th[15], g3.w, v);
    embq[q] = v;
  }
  float di = 1.f/((hq ? ls1 : ls0) + EPSV);
  float4 ebv = *(const float4*)&eb[c0];
  float r0 = di*(ax + embq[0]) + ebv.x;
  float r1 = di*(ay + embq[1]) + ebv.y;
  float r2 = di*(az + embq[2]) + ebv.z;
  float r3 = di*(aw + embq[3]) + ebv.w;
  float p0 = __shfl_xor(r0, 32);
  float p1 = __shfl_xor(r1, 32);
  float p2 = __shfl_xor(r2, 32);
  float p3 = __shfl_xor(r3, 32);
  if (lane < 32){
    float4 bv = *(const float4*)&bias[c0];
    float4 v;
    v.x = 0.5f*(r0 + p0) + bv.x;
    v.y = 0.5f*(r1 + p1) + bv.y;
    v.z = 0.5f*(r2 + p2) + bv.z;
    v.w = 0.5f*(r3 + p3) + bv.w;
    if (relu){
      v.x = fmaxf(v.x, 0.f); v.y = fmaxf(v.y, 0.f);
      v.z = fmaxf(v.z, 0.f); v.w = fmaxf(v.w, 0.f);
    }
    *(float4*)&out[(size_t)n*DD + c0] = v;
  }
}

extern "C" void kernel_launch(void* const* d_in, const int* in_sizes, int n_in,
                              void* d_out, int out_size, void* d_ws, size_t ws_size,
                              hipStream_t stream){
  const float* x       = (const float*)d_in[0];
  const int*   eidx    = (const int*)d_in[1];
  const float* eattr   = (const float*)d_in[2];
  const float* weights = (const float*)d_in[3];
  const float* atts    = (const float*)d_in[4];
  const float* biases  = (const float*)d_in[5];
  const float* edge_ws = (const float*)d_in[6];
  const float* edge_bs = (const float*)d_in[7];
  const int N = in_sizes[0]/DD;
  const int E = in_sizes[1]/2;
  const int Etot = E + N;
  const int* src = eidx;
  const int* dst = eidx + E;

  char* p = (char*)d_ws;
  auto alloc = [&](size_t bytes){ void* r = (void*)p; p += (bytes + 255) & ~(size_t)255; return r; };
  float*    hA      = (float*)alloc((size_t)N*DD*4);
  float*    hB      = (float*)alloc((size_t)N*DD*4);
  __half*   xwh     = (__half*)alloc((size_t)N*HD*2);
  float*    sbuf    = (float*)alloc((size_t)N*4*4);      // aliases counts/cursor during build
  int*      starts  = (int*)alloc((size_t)(N+1)*4);
  int*      srcC    = (int*)alloc((size_t)Etot*4);
  __half*   attrC16 = (__half*)alloc((size_t)Etot*FF*2);
  float*    attrdot = (float*)alloc((size_t)5*Etot*2*4);
  float*    c5      = (float*)alloc(5*34*4);

  int* counts = (int*)sbuf;                       // build-phase alias
  int* cursor = (int*)((char*)sbuf + 65536);      // build-phase alias

  const int ebl = (Etot + 255)/256;

  // CSR build over dst (layer-invariant) + per-layer constants + attr precompute
  hipMemsetAsync(counts, 0, (size_t)N*4, stream);
  k_hist_prec<<<ebl+5, 256, 0, stream>>>(dst, counts, atts, edge_ws, edge_bs, c5, E, Etot, ebl);
  k_scan<<<1, 1024, 0, stream>>>(counts, starts, cursor, N, Etot);
  k_scatter<<<ebl, 256, 0, stream>>>(dst, src, eattr, cursor, srcC, attrC16, E, Etot);
  k_attrdot<<<ebl, 256, 0, stream>>>(attrC16, c5, attrdot, Etot);

  const float* hin = x;
  for (int l = 0; l < 5; l++){
    const float* W   = weights + (size_t)l*DD*HD;
    const float* att = atts    + (size_t)l*HEADS*2*DD;
    const float* b   = biases  + (size_t)l*DD;
    const float* ew  = edge_ws + (size_t)l*HD*FF;
    const float* eb  = edge_bs + (size_t)l*HD;
    const float* c   = c5 + (size_t)l*34;
    const float* adL = attrdot + (size_t)l*Etot*2;
    float* hout = (l == 4) ? (float*)d_out : ((l & 1) ? hB : hA);

    k_gemm_xw<<<(N+31)/32, 256, 0, stream>>>(hin, W, att, xwh, sbuf, N);
    k_aggr<<<N, 256, 0, stream>>>(starts, srcC, attrC16, adL, sbuf, c, xwh, ew, eb, b, hout, N, (l < 4) ? 1 : 0);

    hin = hout;
  }
}

// Round 12
// 419.672 us; speedup vs baseline: 1.1444x; 1.1444x over previous
//
#include <hip/hip_runtime.h>
#include <hip/hip_fp16.h>

#define HEADS 2
#define DD 128
#define FF 16
#define HD 256  // HEADS*DD
#define NEG_SLOPE 0.2f
#define EPSV 1e-16f

static __device__ __forceinline__ float rdlanef(float v, int i){
  return __uint_as_float(__builtin_amdgcn_readlane(__float_as_uint(v), i));
}
static __device__ __forceinline__ int rdlanei(int v, int i){
  return __builtin_amdgcn_readlane(v, i);
}

// ---------------- CSR build ----------------
// blocks [0, ebl): histogram of dst. blocks [ebl, ebl+5): per-layer attr-projection constants.
__global__ void k_hist_prec(const int* __restrict__ dst, int* __restrict__ counts,
                            const float* __restrict__ atts, const float* __restrict__ edge_ws,
                            const float* __restrict__ edge_bs, float* __restrict__ c5,
                            int E, int Etot, int ebl){
  if ((int)blockIdx.x >= ebl){
    int l = blockIdx.x - ebl;
    int t = threadIdx.x;
    const float* att = atts    + (size_t)l*HEADS*2*DD;
    const float* ew  = edge_ws + (size_t)l*HD*FF;
    const float* eb  = edge_bs + (size_t)l*HD;
    float* c = c5 + (size_t)l*34;
    if (t < 32){
      int h = t >> 4, f = t & 15;
      float acc = 0.f;
      for (int d = 0; d < DD; d++) acc += att[h*2*DD + DD + d]*ew[(size_t)(h*DD+d)*FF + f];
      c[h*FF + f] = acc;
    } else if (t < 34){
      int h = t - 32;
      float acc = 0.f;
      for (int d = 0; d < DD; d++) acc += att[h*2*DD + DD + d]*eb[h*DD + d];
      c[32 + h] = acc;
    }
    return;
  }
  int e = blockIdx.x*256 + threadIdx.x;
  if (e >= Etot) return;
  int dn = (e < E) ? dst[e] : (e - E);
  atomicAdd(&counts[dn], 1);
}

__global__ __launch_bounds__(1024) void k_scan(const int* __restrict__ counts, int* __restrict__ starts,
                       int* __restrict__ cursor, int N, int Etot){
  __shared__ int s[1024];
  int t = threadIdx.x;
  const int CHN = (N + 1023) / 1024;
  int lo = t*CHN, hi = min(lo+CHN, N);
  int loc = 0;
  for (int i = lo; i < hi; i++) loc += counts[i];
  s[t] = loc;
  __syncthreads();
  for (int off = 1; off < 1024; off <<= 1){
    int v = (t >= off) ? s[t-off] : 0;
    __syncthreads();
    s[t] += v;
    __syncthreads();
  }
  int run = (t == 0) ? 0 : s[t-1];
  for (int i = lo; i < hi; i++){
    starts[i] = run; cursor[i] = run; run += counts[i];
  }
  if (t == 0) starts[N] = Etot;
}

// scatter: 4B payload only (CSR position -> original edge id)
__global__ void k_scatter(const int* __restrict__ dst, int* __restrict__ cursor,
                          int* __restrict__ eids, int E, int Etot){
  int e = blockIdx.x*256 + threadIdx.x;
  if (e >= Etot) return;
  int dn = (e < E) ? dst[e] : (e - E);
  int pos = atomicAdd(&cursor[dn], 1);
  eids[pos] = e;
}

// coalesced-in-pos pass: build srcC + fp16 attr
__global__ void k_gather_csr(const int* __restrict__ eids, const int* __restrict__ src,
                             const float* __restrict__ eattr, int* __restrict__ srcC,
                             __half* __restrict__ attrC16, int E, int Etot){
  int i = blockIdx.x*256 + threadIdx.x;
  if (i >= Etot) return;
  int eid = eids[i];
  float a[FF];
  if (eid < E){
    srcC[i] = src[eid];
    const float4* in = (const float4*)&eattr[(size_t)eid*FF];
    float4 q0=in[0], q1=in[1], q2=in[2], q3=in[3];
    a[0]=q0.x; a[1]=q0.y; a[2]=q0.z; a[3]=q0.w;
    a[4]=q1.x; a[5]=q1.y; a[6]=q1.z; a[7]=q1.w;
    a[8]=q2.x; a[9]=q2.y; a[10]=q2.z; a[11]=q2.w;
    a[12]=q3.x; a[13]=q3.y; a[14]=q3.z; a[15]=q3.w;
  } else {
    srcC[i] = eid - E;
    #pragma unroll
    for (int f = 0; f < FF; f++) a[f] = 0.f;
  }
  uint4 pk0, pk1;
  {
    __half2 h0 = __floats2half2_rn(a[0],a[1]),  h1 = __floats2half2_rn(a[2],a[3]);
    __half2 h2 = __floats2half2_rn(a[4],a[5]),  h3 = __floats2half2_rn(a[6],a[7]);
    __half2 h4 = __floats2half2_rn(a[8],a[9]),  h5 = __floats2half2_rn(a[10],a[11]);
    __half2 h6 = __floats2half2_rn(a[12],a[13]),h7 = __floats2half2_rn(a[14],a[15]);
    pk0.x=*(unsigned*)&h0; pk0.y=*(unsigned*)&h1; pk0.z=*(unsigned*)&h2; pk0.w=*(unsigned*)&h3;
    pk1.x=*(unsigned*)&h4; pk1.y=*(unsigned*)&h5; pk1.z=*(unsigned*)&h6; pk1.w=*(unsigned*)&h7;
  }
  uint4* ob = (uint4*)&attrC16[(size_t)i*FF];
  ob[0] = pk0; ob[1] = pk1;
}

// coalesced pass: attrdot[l][i][2] = attrC16[i] . c5[l]
__global__ void k_attrdot(const __half* __restrict__ attrC16, const float* __restrict__ c5,
                          float* __restrict__ attrdot, int Etot){
  int i = blockIdx.x*256 + threadIdx.x;
  if (i >= Etot) return;
  const uint4* ap = (const uint4*)&attrC16[(size_t)i*FF];
  uint4 p0 = ap[0], p1 = ap[1];
  float a[FF];
  {
    float2 f;
    f = __half22float2(*(__half2*)&p0.x); a[0]=f.x;  a[1]=f.y;
    f = __half22float2(*(__half2*)&p0.y); a[2]=f.x;  a[3]=f.y;
    f = __half22float2(*(__half2*)&p0.z); a[4]=f.x;  a[5]=f.y;
    f = __half22float2(*(__half2*)&p0.w); a[6]=f.x;  a[7]=f.y;
    f = __half22float2(*(__half2*)&p1.x); a[8]=f.x;  a[9]=f.y;
    f = __half22float2(*(__half2*)&p1.y); a[10]=f.x; a[11]=f.y;
    f = __half22float2(*(__half2*)&p1.z); a[12]=f.x; a[13]=f.y;
    f = __half22float2(*(__half2*)&p1.w); a[14]=f.x; a[15]=f.y;
  }
  #pragma unroll
  for (int l = 0; l < 5; l++){
    const float* cl = c5 + (size_t)l*34;
    float d0 = 0.f, d1 = 0.f;
    #pragma unroll
    for (int f = 0; f < FF; f++){
      d0 = fmaf(a[f], cl[f], d0);
      d1 = fmaf(a[f], cl[FF+f], d1);
    }
    *(float2*)&attrdot[((size_t)l*Etot + i)*2] = make_float2(d0, d1);
  }
}

// xw[N,256] (fp16) = h[N,128] @ W[128,256]; fused s[n][4] = {si_h0, si_h1, sj_h0, sj_h1}
// 16-row tiles -> 625 blocks (R8 config; 32-row/313-block grid starved CUs in R10).
__global__ __launch_bounds__(256) void k_gemm_xw(const float* __restrict__ h, const float* __restrict__ W,
                         const float* __restrict__ att, __half* __restrict__ xwh,
                         float* __restrict__ sbuf, int N){
  __shared__ float sx[16][DD];
  int r0 = blockIdx.x * 16;
  int rows = min(16, N - r0);
  int t = threadIdx.x;
  for (int idx = t; idx < 16*(DD/4); idx += 256){
    int r = idx >> 5, kq = idx & 31;
    float4 v = make_float4(0.f,0.f,0.f,0.f);
    if (r < rows) v = *(const float4*)&h[(size_t)(r0+r)*DD + kq*4];
    *(float4*)&sx[r][kq*4] = v;
  }
  __syncthreads();
  int tx = t & 63, ty = t >> 6;
  int c0 = tx*4;
  float4 acc[4];
  #pragma unroll
  for (int r = 0; r < 4; r++) acc[r] = make_float4(0.f,0.f,0.f,0.f);
  #pragma unroll 4
  for (int kq = 0; kq < 32; kq++){
    float4 w0 = *(const float4*)&W[(size_t)(kq*4+0)*HD + c0];
    float4 w1 = *(const float4*)&W[(size_t)(kq*4+1)*HD + c0];
    float4 w2 = *(const float4*)&W[(size_t)(kq*4+2)*HD + c0];
    float4 w3 = *(const float4*)&W[(size_t)(kq*4+3)*HD + c0];
    #pragma unroll
    for (int r = 0; r < 4; r++){
      float4 hv = *(const float4*)&sx[ty*4+r][kq*4];
      acc[r].x = fmaf(hv.x, w0.x, acc[r].x); acc[r].y = fmaf(hv.x, w0.y, acc[r].y);
      acc[r].z = fmaf(hv.x, w0.z, acc[r].z); acc[r].w = fmaf(hv.x, w0.w, acc[r].w);
      acc[r].x = fmaf(hv.y, w1.x, acc[r].x); acc[r].y = fmaf(hv.y, w1.y, acc[r].y);
      acc[r].z = fmaf(hv.y, w1.z, acc[r].z); acc[r].w = fmaf(hv.y, w1.w, acc[r].w);
      acc[r].x = fmaf(hv.z, w2.x, acc[r].x); acc[r].y = fmaf(hv.z, w2.y, acc[r].y);
      acc[r].z = fmaf(hv.z, w2.z, acc[r].z); acc[r].w = fmaf(hv.z, w2.w, acc[r].w);
      acc[r].x = fmaf(hv.w, w3.x, acc[r].x); acc[r].y = fmaf(hv.w, w3.y, acc[r].y);
      acc[r].z = fmaf(hv.w, w3.z, acc[r].z); acc[r].w = fmaf(hv.w, w3.w, acc[r].w);
    }
  }
  #pragma unroll
  for (int r = 0; r < 4; r++){
    if (ty*4+r < rows){
      __half2 p0 = __floats2half2_rn(acc[r].x, acc[r].y);
      __half2 p1 = __floats2half2_rn(acc[r].z, acc[r].w);
      uint2 pk;
      pk.x = *(unsigned*)&p0;
      pk.y = *(unsigned*)&p1;
      *(uint2*)&xwh[(size_t)(r0+ty*4+r)*HD + c0] = pk;
    }
  }
  int hsel = tx >> 5;
  int cm = c0 & 127;
  float4 ai = *(const float4*)&att[hsel*2*DD + cm];
  float4 aj = *(const float4*)&att[hsel*2*DD + DD + cm];
  #pragma unroll
  for (int r = 0; r < 4; r++){
    float pi = acc[r].x*ai.x + acc[r].y*ai.y + acc[r].z*ai.z + acc[r].w*ai.w;
    float pj = acc[r].x*aj.x + acc[r].y*aj.y + acc[r].z*aj.z + acc[r].w*aj.w;
    #pragma unroll
    for (int off = 16; off; off >>= 1){
      pi += __shfl_xor(pi, off);
      pj += __shfl_xor(pj, off);
    }
    int row = ty*4 + r;
    if ((tx & 31) == 0 && row < rows){
      sbuf[(size_t)(r0+row)*4 + 0 + hsel] = pi;
      sbuf[(size_t)(r0+row)*4 + 2 + hsel] = pj;
    }
  }
}

// Head-split aggregation: pass hh gathers only head hh's 128 cols (256B/edge = 2 lines,
// 2.56MB working set -> fits 4MB XCD L2). Wave per node; lane owns 2 cols (4B load).
// Pass 0 writes tmp[n][128]; pass 1 combines + bias (+relu).
#define BB 8
__global__ __launch_bounds__(256) void k_aggr_h(const int* __restrict__ starts, const int* __restrict__ srcC,
                      const __half* __restrict__ attrC16, const float* __restrict__ adL,
                      const float* __restrict__ s, const float* __restrict__ c,
                      const __half* __restrict__ xwh, const float* __restrict__ ew,
                      const float* __restrict__ eb, const float* __restrict__ bias,
                      float* __restrict__ tmph, float* __restrict__ out,
                      int N, int relu, int hh){
  int lane = threadIdx.x & 63, wid = threadIdx.x >> 6;
  int n = blockIdx.x*4 + wid;
  if (n >= N) return;

  float c32h = c[32 + hh];
  float sdh  = s[(size_t)n*4 + hh];
  int st = starts[n];
  int deg = starts[n+1] - st;

  int f2 = lane & 15;
  const __half* xbase = xwh + hh*DD + lane*2;   // lane's 2-col slice of head hh

  float acc0 = 0.f, acc1 = 0.f, ls = 0.f, tacc = 0.f;

  for (int base = 0; base < deg; base += 64){
    int cnt = min(64, deg - base);
    float ee = 0.f; int msrc = 0;
    if (lane < cnt){
      int idx = st + base + lane;
      msrc = srcC[idx];
      float sj = s[(size_t)msrc*4 + 2 + hh];
      float ad = adL[(size_t)idx*2 + hh];
      float x = sdh + sj + c32h + ad;
      x = (x > 0.f) ? x : NEG_SLOPE*x;
      ee = expf(x);
      ls += ee;
    }
    const __half* abase = &attrC16[(size_t)(st+base)*FF + f2];
    int i = 0;
    for (; i + BB <= cnt; i += BB){
      unsigned u[BB];
      float av[BB];
      #pragma unroll
      for (int k = 0; k < BB; k++){
        int sn = rdlanei(msrc, i+k);
        u[k] = *(const unsigned*)(xbase + (size_t)sn*HD);
      }
      #pragma unroll
      for (int k = 0; k < BB; k++) av[k] = __half2float(abase[(size_t)(i+k)*FF]);
      #pragma unroll
      for (int k = 0; k < BB; k++){
        float w = rdlanef(ee, i+k);
        float2 xv = __half22float2(*(__half2*)&u[k]);
        acc0 = fmaf(w, xv.x, acc0);
        acc1 = fmaf(w, xv.y, acc1);
        tacc = fmaf(w, av[k], tacc);
      }
    }
    for (; i < cnt; i++){
      int sn = rdlanei(msrc, i);
      float w = rdlanef(ee, i);
      unsigned u0 = *(const unsigned*)(xbase + (size_t)sn*HD);
      float av0 = __half2float(abase[(size_t)i*FF]);
      float2 xv = __half22float2(*(__half2*)&u0);
      acc0 = fmaf(w, xv.x, acc0);
      acc1 = fmaf(w, xv.y, acc1);
      tacc = fmaf(w, av0, tacc);
    }
  }
  #pragma unroll
  for (int off = 32; off; off >>= 1) ls += __shfl_xor(ls, off);
  // every lane iterated ALL edges for tacc: lane f (f<16) holds complete t[hh][f]

  // epilogue: factored edge-emb for my 2 cols + normalize
  int c2 = lane*2;                     // col within head (0..126)
  float th[FF];
  #pragma unroll
  for (int f = 0; f < FF; f++) th[f] = rdlanef(tacc, f);
  float emb0 = 0.f, emb1 = 0.f;
  {
    const float4* e0p = (const float4*)&ew[(size_t)(hh*DD + c2)*FF];
    const float4* e1p = (const float4*)&ew[(size_t)(hh*DD + c2 + 1)*FF];
    #pragma unroll
    for (int q = 0; q < 4; q++){
      float4 g0 = e0p[q], g1 = e1p[q];
      emb0 = fmaf(th[q*4+0], g0.x, emb0); emb0 = fmaf(th[q*4+1], g0.y, emb0);
      emb0 = fmaf(th[q*4+2], g0.z, emb0); emb0 = fmaf(th[q*4+3], g0.w, emb0);
      emb1 = fmaf(th[q*4+0], g1.x, emb1); emb1 = fmaf(th[q*4+1], g1.y, emb1);
      emb1 = fmaf(th[q*4+2], g1.z, emb1); emb1 = fmaf(th[q*4+3], g1.w, emb1);
    }
  }
  float di = 1.f/(ls + EPSV);
  float2 ebv = *(const float2*)&eb[hh*DD + c2];
  float p0 = di*(acc0 + emb0) + ebv.x;
  float p1 = di*(acc1 + emb1) + ebv.y;
  if (hh == 0){
    *(float2*)&tmph[(size_t)n*DD + c2] = make_float2(p0, p1);
  } else {
    float2 t0 = *(const float2*)&tmph[(size_t)n*DD + c2];
    float2 bv = *(const float2*)&bias[c2];
    float o0 = 0.5f*(t0.x + p0) + bv.x;
    float o1 = 0.5f*(t0.y + p1) + bv.y;
    if (relu){ o0 = fmaxf(o0, 0.f); o1 = fmaxf(o1, 0.f); }
    *(float2*)&out[(size_t)n*DD + c2] = make_float2(o0, o1);
  }
}

extern "C" void kernel_launch(void* const* d_in, const int* in_sizes, int n_in,
                              void* d_out, int out_size, void* d_ws, size_t ws_size,
                              hipStream_t stream){
  const float* x       = (const float*)d_in[0];
  const int*   eidx    = (const int*)d_in[1];
  const float* eattr   = (const float*)d_in[2];
  const float* weights = (const float*)d_in[3];
  const float* atts    = (const float*)d_in[4];
  const float* biases  = (const float*)d_in[5];
  const float* edge_ws = (const float*)d_in[6];
  const float* edge_bs = (const float*)d_in[7];
  const int N = in_sizes[0]/DD;
  const int E = in_sizes[1]/2;
  const int Etot = E + N;
  const int* src = eidx;
  const int* dst = eidx + E;

  char* p = (char*)d_ws;
  auto alloc = [&](size_t bytes){ void* r = (void*)p; p += (bytes + 255) & ~(size_t)255; return r; };
  float*    hA      = (float*)alloc((size_t)N*DD*4);
  float*    hB      = (float*)alloc((size_t)N*DD*4);
  float*    tmph    = (float*)alloc((size_t)N*DD*4);
  __half*   xwh     = (__half*)alloc((size_t)N*HD*2);
  float*    sbuf    = (float*)alloc((size_t)N*4*4);      // aliases counts/cursor during build
  int*      starts  = (int*)alloc((size_t)(N+1)*4);
  int*      srcC    = (int*)alloc((size_t)Etot*4);
  int*      eids    = (int*)alloc((size_t)Etot*4);
  __half*   attrC16 = (__half*)alloc((size_t)Etot*FF*2);
  float*    attrdot = (float*)alloc((size_t)5*Etot*2*4);
  float*    c5      = (float*)alloc(5*34*4);

  int* counts = (int*)sbuf;                       // build-phase alias
  int* cursor = (int*)((char*)sbuf + 65536);      // build-phase alias

  const int ebl = (Etot + 255)/256;

  // CSR build over dst (layer-invariant) + per-layer constants + attr precompute
  hipMemsetAsync(counts, 0, (size_t)N*4, stream);
  k_hist_prec<<<ebl+5, 256, 0, stream>>>(dst, counts, atts, edge_ws, edge_bs, c5, E, Etot, ebl);
  k_scan<<<1, 1024, 0, stream>>>(counts, starts, cursor, N, Etot);
  k_scatter<<<ebl, 256, 0, stream>>>(dst, cursor, eids, E, Etot);
  k_gather_csr<<<ebl, 256, 0, stream>>>(eids, src, eattr, srcC, attrC16, E, Etot);
  k_attrdot<<<ebl, 256, 0, stream>>>(attrC16, c5, attrdot, Etot);

  const float* hin = x;
  const int agrid = (N+3)/4;
  for (int l = 0; l < 5; l++){
    const float* W   = weights + (size_t)l*DD*HD;
    const float* att = atts    + (size_t)l*HEADS*2*DD;
    const float* b   = biases  + (size_t)l*DD;
    const float* ew  = edge_ws + (size_t)l*HD*FF;
    const float* eb  = edge_bs + (size_t)l*HD;
    const float* c   = c5 + (size_t)l*34;
    const float* adL = attrdot + (size_t)l*Etot*2;
    float* hout = (l == 4) ? (float*)d_out : ((l & 1) ? hB : hA);
    int relu = (l < 4) ? 1 : 0;

    k_gemm_xw<<<(N+15)/16, 256, 0, stream>>>(hin, W, att, xwh, sbuf, N);
    k_aggr_h<<<agrid, 256, 0, stream>>>(starts, srcC, attrC16, adL, sbuf, c, xwh, ew, eb, b, tmph, hout, N, relu, 0);
    k_aggr_h<<<agrid, 256, 0, stream>>>(starts, srcC, attrC16, adL, sbuf, c, xwh, ew, eb, b, tmph, hout, N, relu, 1);

    hin = hout;
  }
}

// Round 13
// 410.094 us; speedup vs baseline: 1.1711x; 1.0234x over previous
//
#include <hip/hip_runtime.h>
#include <hip/hip_fp16.h>

#define HEADS 2
#define DD 128
#define FF 16
#define HD 256  // HEADS*DD
#define NEG_SLOPE 0.2f
#define EPSV 1e-16f

static __device__ __forceinline__ float rdlanef(float v, int i){
  return __uint_as_float(__builtin_amdgcn_readlane(__float_as_uint(v), i));
}
static __device__ __forceinline__ int rdlanei(int v, int i){
  return __builtin_amdgcn_readlane(v, i);
}
static __device__ __forceinline__ float4 h4f(uint2 u){
  float2 f0 = __half22float2(*(__half2*)&u.x);
  float2 f1 = __half22float2(*(__half2*)&u.y);
  return make_float4(f0.x, f0.y, f1.x, f1.y);
}

// ---------------- CSR build ----------------
// blocks [0,ebl): dst histogram. [ebl,ebl+5): c5 constants. [ebl+5,ebl+165): W->fp16.
__global__ void k_hist_prec(const int* __restrict__ dst, int* __restrict__ counts,
                            const float* __restrict__ atts, const float* __restrict__ edge_ws,
                            const float* __restrict__ edge_bs, const float* __restrict__ weights,
                            float* __restrict__ c5, __half* __restrict__ wh,
                            int E, int Etot, int ebl){
  int bid = blockIdx.x;
  if (bid >= ebl){
    int k = bid - ebl;
    if (k < 5){
      int l = k, t = threadIdx.x;
      const float* att = atts    + (size_t)l*HEADS*2*DD;
      const float* ew  = edge_ws + (size_t)l*HD*FF;
      const float* eb  = edge_bs + (size_t)l*HD;
      float* c = c5 + (size_t)l*34;
      if (t < 32){
        int h = t >> 4, f = t & 15;
        float acc = 0.f;
        for (int d = 0; d < DD; d++) acc += att[h*2*DD + DD + d]*ew[(size_t)(h*DD+d)*FF + f];
        c[h*FF + f] = acc;
      } else if (t < 34){
        int h = t - 32;
        float acc = 0.f;
        for (int d = 0; d < DD; d++) acc += att[h*2*DD + DD + d]*eb[h*DD + d];
        c[32 + h] = acc;
      }
    } else {
      int base = (k - 5)*1024 + threadIdx.x*4;   // 5*DD*HD = 163840 = 160*1024
      float4 w = *(const float4*)&weights[base];
      __half2 p0 = __floats2half2_rn(w.x, w.y);
      __half2 p1 = __floats2half2_rn(w.z, w.w);
      uint2 pk; pk.x = *(unsigned*)&p0; pk.y = *(unsigned*)&p1;
      *(uint2*)&wh[base] = pk;
    }
    return;
  }
  int e = bid*256 + threadIdx.x;
  if (e >= Etot) return;
  int dn = (e < E) ? dst[e] : (e - E);
  atomicAdd(&counts[dn], 1);
}

__global__ __launch_bounds__(1024) void k_scan(const int* __restrict__ counts, int* __restrict__ starts,
                       int* __restrict__ cursor, int N, int Etot){
  __shared__ int s[1024];
  int t = threadIdx.x;
  const int CHN = (N + 1023) / 1024;
  int lo = t*CHN, hi = min(lo+CHN, N);
  int loc = 0;
  for (int i = lo; i < hi; i++) loc += counts[i];
  s[t] = loc;
  __syncthreads();
  for (int off = 1; off < 1024; off <<= 1){
    int v = (t >= off) ? s[t-off] : 0;
    __syncthreads();
    s[t] += v;
    __syncthreads();
  }
  int run = (t == 0) ? 0 : s[t-1];
  for (int i = lo; i < hi; i++){
    starts[i] = run; cursor[i] = run; run += counts[i];
  }
  if (t == 0) starts[N] = Etot;
}

// scatter: 4B payload (CSR position -> original edge id)
__global__ void k_scatter(const int* __restrict__ dst, int* __restrict__ cursor,
                          int* __restrict__ eids, int E, int Etot){
  int e = blockIdx.x*256 + threadIdx.x;
  if (e >= Etot) return;
  int dn = (e < E) ? dst[e] : (e - E);
  int pos = atomicAdd(&cursor[dn], 1);
  eids[pos] = e;
}

// build srcC, dstC, fp16 attr in CSR order
__global__ void k_gather_csr(const int* __restrict__ eids, const int* __restrict__ src,
                             const int* __restrict__ dst, const float* __restrict__ eattr,
                             int* __restrict__ srcC, int* __restrict__ dstC,
                             __half* __restrict__ attrC16, int E, int Etot){
  int i = blockIdx.x*256 + threadIdx.x;
  if (i >= Etot) return;
  int eid = eids[i];
  float a[FF];
  if (eid < E){
    srcC[i] = src[eid];
    dstC[i] = dst[eid];
    const float4* in = (const float4*)&eattr[(size_t)eid*FF];
    float4 q0=in[0], q1=in[1], q2=in[2], q3=in[3];
    a[0]=q0.x; a[1]=q0.y; a[2]=q0.z; a[3]=q0.w;
    a[4]=q1.x; a[5]=q1.y; a[6]=q1.z; a[7]=q1.w;
    a[8]=q2.x; a[9]=q2.y; a[10]=q2.z; a[11]=q2.w;
    a[12]=q3.x; a[13]=q3.y; a[14]=q3.z; a[15]=q3.w;
  } else {
    srcC[i] = eid - E;
    dstC[i] = eid - E;
    #pragma unroll
    for (int f = 0; f < FF; f++) a[f] = 0.f;
  }
  uint4 pk0, pk1;
  {
    __half2 h0 = __floats2half2_rn(a[0],a[1]),  h1 = __floats2half2_rn(a[2],a[3]);
    __half2 h2 = __floats2half2_rn(a[4],a[5]),  h3 = __floats2half2_rn(a[6],a[7]);
    __half2 h4 = __floats2half2_rn(a[8],a[9]),  h5 = __floats2half2_rn(a[10],a[11]);
    __half2 h6 = __floats2half2_rn(a[12],a[13]),h7 = __floats2half2_rn(a[14],a[15]);
    pk0.x=*(unsigned*)&h0; pk0.y=*(unsigned*)&h1; pk0.z=*(unsigned*)&h2; pk0.w=*(unsigned*)&h3;
    pk1.x=*(unsigned*)&h4; pk1.y=*(unsigned*)&h5; pk1.z=*(unsigned*)&h6; pk1.w=*(unsigned*)&h7;
  }
  uint4* ob = (uint4*)&attrC16[(size_t)i*FF];
  ob[0] = pk0; ob[1] = pk1;
}

// coalesced pass: attrdot[l][i][2] = attr[i] . c5[l]
__global__ void k_attrdot(const __half* __restrict__ attrC16, const float* __restrict__ c5,
                          float* __restrict__ attrdot, int Etot){
  int i = blockIdx.x*256 + threadIdx.x;
  if (i >= Etot) return;
  const uint4* ap = (const uint4*)&attrC16[(size_t)i*FF];
  uint4 p0 = ap[0], p1 = ap[1];
  float a[FF];
  {
    float2 f;
    f = __half22float2(*(__half2*)&p0.x); a[0]=f.x;  a[1]=f.y;
    f = __half22float2(*(__half2*)&p0.y); a[2]=f.x;  a[3]=f.y;
    f = __half22float2(*(__half2*)&p0.z); a[4]=f.x;  a[5]=f.y;
    f = __half22float2(*(__half2*)&p0.w); a[6]=f.x;  a[7]=f.y;
    f = __half22float2(*(__half2*)&p1.x); a[8]=f.x;  a[9]=f.y;
    f = __half22float2(*(__half2*)&p1.y); a[10]=f.x; a[11]=f.y;
    f = __half22float2(*(__half2*)&p1.z); a[12]=f.x; a[13]=f.y;
    f = __half22float2(*(__half2*)&p1.w); a[14]=f.x; a[15]=f.y;
  }
  #pragma unroll
  for (int l = 0; l < 5; l++){
    const float* cl = c5 + (size_t)l*34;
    float d0 = 0.f, d1 = 0.f;
    #pragma unroll
    for (int f = 0; f < FF; f++){
      d0 = fmaf(a[f], cl[f], d0);
      d1 = fmaf(a[f], cl[FF+f], d1);
    }
    *(float2*)&attrdot[((size_t)l*Etot + i)*2] = make_float2(d0, d1);
  }
}

// xw[N,256] (fp16) = h[N,128] @ Wh[128,256](fp16); fused s[n][4]
__global__ __launch_bounds__(256) void k_gemm_xw(const float* __restrict__ h, const __half* __restrict__ Wh,
                         const float* __restrict__ att, __half* __restrict__ xwh,
                         float* __restrict__ sbuf, int N){
  __shared__ float sx[16][DD];
  int r0 = blockIdx.x * 16;
  int rows = min(16, N - r0);
  int t = threadIdx.x;
  for (int idx = t; idx < 16*(DD/4); idx += 256){
    int r = idx >> 5, kq = idx & 31;
    float4 v = make_float4(0.f,0.f,0.f,0.f);
    if (r < rows) v = *(const float4*)&h[(size_t)(r0+r)*DD + kq*4];
    *(float4*)&sx[r][kq*4] = v;
  }
  __syncthreads();
  int tx = t & 63, ty = t >> 6;
  int c0 = tx*4;
  float4 acc[4];
  #pragma unroll
  for (int r = 0; r < 4; r++) acc[r] = make_float4(0.f,0.f,0.f,0.f);
  #pragma unroll 4
  for (int kq = 0; kq < 32; kq++){
    float4 w0 = h4f(*(const uint2*)&Wh[(size_t)(kq*4+0)*HD + c0]);
    float4 w1 = h4f(*(const uint2*)&Wh[(size_t)(kq*4+1)*HD + c0]);
    float4 w2 = h4f(*(const uint2*)&Wh[(size_t)(kq*4+2)*HD + c0]);
    float4 w3 = h4f(*(const uint2*)&Wh[(size_t)(kq*4+3)*HD + c0]);
    #pragma unroll
    for (int r = 0; r < 4; r++){
      float4 hv = *(const float4*)&sx[ty*4+r][kq*4];
      acc[r].x = fmaf(hv.x, w0.x, acc[r].x); acc[r].y = fmaf(hv.x, w0.y, acc[r].y);
      acc[r].z = fmaf(hv.x, w0.z, acc[r].z); acc[r].w = fmaf(hv.x, w0.w, acc[r].w);
      acc[r].x = fmaf(hv.y, w1.x, acc[r].x); acc[r].y = fmaf(hv.y, w1.y, acc[r].y);
      acc[r].z = fmaf(hv.y, w1.z, acc[r].z); acc[r].w = fmaf(hv.y, w1.w, acc[r].w);
      acc[r].x = fmaf(hv.z, w2.x, acc[r].x); acc[r].y = fmaf(hv.z, w2.y, acc[r].y);
      acc[r].z = fmaf(hv.z, w2.z, acc[r].z); acc[r].w = fmaf(hv.z, w2.w, acc[r].w);
      acc[r].x = fmaf(hv.w, w3.x, acc[r].x); acc[r].y = fmaf(hv.w, w3.y, acc[r].y);
      acc[r].z = fmaf(hv.w, w3.z, acc[r].z); acc[r].w = fmaf(hv.w, w3.w, acc[r].w);
    }
  }
  #pragma unroll
  for (int r = 0; r < 4; r++){
    if (ty*4+r < rows){
      __half2 p0 = __floats2half2_rn(acc[r].x, acc[r].y);
      __half2 p1 = __floats2half2_rn(acc[r].z, acc[r].w);
      uint2 pk;
      pk.x = *(unsigned*)&p0;
      pk.y = *(unsigned*)&p1;
      *(uint2*)&xwh[(size_t)(r0+ty*4+r)*HD + c0] = pk;
    }
  }
  int hsel = tx >> 5;
  int cm = c0 & 127;
  float4 ai = *(const float4*)&att[hsel*2*DD + cm];
  float4 aj = *(const float4*)&att[hsel*2*DD + DD + cm];
  #pragma unroll
  for (int r = 0; r < 4; r++){
    float pi = acc[r].x*ai.x + acc[r].y*ai.y + acc[r].z*ai.z + acc[r].w*ai.w;
    float pj = acc[r].x*aj.x + acc[r].y*aj.y + acc[r].z*aj.z + acc[r].w*aj.w;
    #pragma unroll
    for (int off = 16; off; off >>= 1){
      pi += __shfl_xor(pi, off);
      pj += __shfl_xor(pj, off);
    }
    int row = ty*4 + r;
    if ((tx & 31) == 0 && row < rows){
      sbuf[(size_t)(r0+row)*4 + 0 + hsel] = pi;
      sbuf[(size_t)(r0+row)*4 + 2 + hsel] = pj;
    }
  }
}

// edge-parallel: ea[i] = {exp(lrelu(alpha_h0)), exp(lrelu(alpha_h1))} as half2
__global__ void k_ea(const int* __restrict__ srcC, const int* __restrict__ dstC,
                     const float* __restrict__ adL, const float* __restrict__ s,
                     const float* __restrict__ c, __half2* __restrict__ ea, int Etot){
  int i = blockIdx.x*256 + threadIdx.x;
  if (i >= Etot) return;
  int sn = srcC[i], dn = dstC[i];
  float2 si = *(const float2*)&s[(size_t)dn*4];     // si_h0, si_h1 (dn sorted -> cached)
  float2 sj = *(const float2*)&s[(size_t)sn*4+2];   // sj_h0, sj_h1 (random, 1 line)
  float2 ad = *(const float2*)&adL[(size_t)i*2];
  float x0 = si.x + sj.x + c[32] + ad.x;
  float x1 = si.y + sj.y + c[33] + ad.y;
  x0 = (x0 > 0.f) ? x0 : NEG_SLOPE*x0;
  x1 = (x1 > 0.f) ? x1 : NEG_SLOPE*x1;
  ea[i] = __floats2half2_rn(expf(x0), expf(x1));
}

// Fused both-head aggregation. Block = 1 node, 4 waves: wave w -> head hh=w>>1,
// parity par=w&1 (edges st+2j+par). No alpha work (reads precomputed ea).
// LDS merge; wave 0 does epilogue + output.
#define BB 8
__global__ __launch_bounds__(256) void k_aggr2(const int* __restrict__ starts, const int* __restrict__ srcC,
                      const __half* __restrict__ attrC16, const __half2* __restrict__ ea,
                      const __half* __restrict__ xwh, const float* __restrict__ ew,
                      const float* __restrict__ eb, const float* __restrict__ bias,
                      float* __restrict__ out, int N, int relu){
  int lane = threadIdx.x & 63, wv = threadIdx.x >> 6;
  int n = blockIdx.x;
  int hh = wv >> 1, par = wv & 1;

  int st = starts[n];
  int deg = starts[n+1] - st;
  int cw = (deg + 1 - par) >> 1;   // edges with index ≡ par (mod 2)

  int f2 = lane & 15;
  const __half* xbase = xwh + hh*DD + lane*2;     // lane's 2 cols of head hh

  float acc0 = 0.f, acc1 = 0.f, ls = 0.f, tacc = 0.f;

  for (int jb = 0; jb < cw; jb += 64){
    int cnt = min(64, cw - jb);
    float ee = 0.f; int msrc = 0;
    if (lane < cnt){
      int g = st + 2*(jb + lane) + par;
      msrc = srcC[g];
      float2 e2 = __half22float2(ea[g]);
      ee = hh ? e2.y : e2.x;
      ls += ee;
    }
    const __half* abase = attrC16 + (size_t)(st + 2*jb + par)*FF + f2;  // + i*2*FF
    int i = 0;
    for (; i + BB <= cnt; i += BB){
      unsigned u[BB];
      float av[BB];
      #pragma unroll
      for (int k = 0; k < BB; k++){
        int sn = rdlanei(msrc, i+k);
        u[k] = *(const unsigned*)(xbase + (size_t)sn*HD);
      }
      #pragma unroll
      for (int k = 0; k < BB; k++) av[k] = __half2float(abase[(size_t)(i+k)*2*FF]);
      #pragma unroll
      for (int k = 0; k < BB; k++){
        float w = rdlanef(ee, i+k);
        float2 xv = __half22float2(*(__half2*)&u[k]);
        acc0 = fmaf(w, xv.x, acc0);
        acc1 = fmaf(w, xv.y, acc1);
        tacc = fmaf(w, av[k], tacc);
      }
    }
    for (; i < cnt; i++){
      int sn = rdlanei(msrc, i);
      float w = rdlanef(ee, i);
      unsigned u0 = *(const unsigned*)(xbase + (size_t)sn*HD);
      float av0 = __half2float(abase[(size_t)i*2*FF]);
      float2 xv = __half22float2(*(__half2*)&u0);
      acc0 = fmaf(w, xv.x, acc0);
      acc1 = fmaf(w, xv.y, acc1);
      tacc = fmaf(w, av0, tacc);
    }
  }
  #pragma unroll
  for (int off = 32; off; off >>= 1) ls += __shfl_xor(ls, off);

  __shared__ float m_acc[4][64][2];
  __shared__ float m_t[4][64];
  __shared__ float m_ls[4];
  m_acc[wv][lane][0] = acc0;
  m_acc[wv][lane][1] = acc1;
  m_t[wv][lane] = tacc;
  if (lane == 0) m_ls[wv] = ls;
  __syncthreads();
  if (wv != 0) return;

  // per-head sums
  float a00 = m_acc[0][lane][0] + m_acc[1][lane][0];
  float a01 = m_acc[0][lane][1] + m_acc[1][lane][1];
  float a10 = m_acc[2][lane][0] + m_acc[3][lane][0];
  float a11 = m_acc[2][lane][1] + m_acc[3][lane][1];
  float ls0 = m_ls[0] + m_ls[1];
  float ls1 = m_ls[2] + m_ls[3];
  float th0[FF], th1[FF];
  #pragma unroll
  for (int f = 0; f < FF; f++){
    th0[f] = m_t[0][f] + m_t[1][f];
    th1[f] = m_t[2][f] + m_t[3][f];
  }
  int c2 = lane*2;
  float emb00=0.f, emb01=0.f, emb10=0.f, emb11=0.f;
  {
    const float4* e00 = (const float4*)&ew[(size_t)(c2)*FF];
    const float4* e01 = (const float4*)&ew[(size_t)(c2+1)*FF];
    const float4* e10 = (const float4*)&ew[(size_t)(DD+c2)*FF];
    const float4* e11 = (const float4*)&ew[(size_t)(DD+c2+1)*FF];
    #pragma unroll
    for (int q = 0; q < 4; q++){
      float4 g00 = e00[q], g01 = e01[q], g10 = e10[q], g11 = e11[q];
      emb00 = fmaf(th0[q*4+0],g00.x,emb00); emb00 = fmaf(th0[q*4+1],g00.y,emb00);
      emb00 = fmaf(th0[q*4+2],g00.z,emb00); emb00 = fmaf(th0[q*4+3],g00.w,emb00);
      emb01 = fmaf(th0[q*4+0],g01.x,emb01); emb01 = fmaf(th0[q*4+1],g01.y,emb01);
      emb01 = fmaf(th0[q*4+2],g01.z,emb01); emb01 = fmaf(th0[q*4+3],g01.w,emb01);
      emb10 = fmaf(th1[q*4+0],g10.x,emb10); emb10 = fmaf(th1[q*4+1],g10.y,emb10);
      emb10 = fmaf(th1[q*4+2],g10.z,emb10); emb10 = fmaf(th1[q*4+3],g10.w,emb10);
      emb11 = fmaf(th1[q*4+0],g11.x,emb11); emb11 = fmaf(th1[q*4+1],g11.y,emb11);
      emb11 = fmaf(th1[q*4+2],g11.z,emb11); emb11 = fmaf(th1[q*4+3],g11.w,emb11);
    }
  }
  float di0 = 1.f/(ls0 + EPSV);
  float di1 = 1.f/(ls1 + EPSV);
  float2 eb0 = *(const float2*)&eb[c2];
  float2 eb1 = *(const float2*)&eb[DD + c2];
  float p00 = di0*(a00 + emb00) + eb0.x;
  float p01 = di0*(a01 + emb01) + eb0.y;
  float p10 = di1*(a10 + emb10) + eb1.x;
  float p11 = di1*(a11 + emb11) + eb1.y;
  float2 bv = *(const float2*)&bias[c2];
  float o0 = 0.5f*(p00 + p10) + bv.x;
  float o1 = 0.5f*(p01 + p11) + bv.y;
  if (relu){ o0 = fmaxf(o0, 0.f); o1 = fmaxf(o1, 0.f); }
  *(float2*)&out[(size_t)n*DD + c2] = make_float2(o0, o1);
}

extern "C" void kernel_launch(void* const* d_in, const int* in_sizes, int n_in,
                              void* d_out, int out_size, void* d_ws, size_t ws_size,
                              hipStream_t stream){
  const float* x       = (const float*)d_in[0];
  const int*   eidx    = (const int*)d_in[1];
  const float* eattr   = (const float*)d_in[2];
  const float* weights = (const float*)d_in[3];
  const float* atts    = (const float*)d_in[4];
  const float* biases  = (const float*)d_in[5];
  const float* edge_ws = (const float*)d_in[6];
  const float* edge_bs = (const float*)d_in[7];
  const int N = in_sizes[0]/DD;
  const int E = in_sizes[1]/2;
  const int Etot = E + N;
  const int* src = eidx;
  const int* dst = eidx + E;

  char* p = (char*)d_ws;
  auto alloc = [&](size_t bytes){ void* r = (void*)p; p += (bytes + 255) & ~(size_t)255; return r; };
  float*    hA      = (float*)alloc((size_t)N*DD*4);
  float*    hB      = (float*)alloc((size_t)N*DD*4);
  __half*   xwh     = (__half*)alloc((size_t)N*HD*2);
  float*    sbuf    = (float*)alloc((size_t)N*4*4);      // aliases counts/cursor during build
  int*      starts  = (int*)alloc((size_t)(N+1)*4);
  int*      srcC    = (int*)alloc((size_t)Etot*4);
  int*      dstC    = (int*)alloc((size_t)Etot*4);
  int*      eids    = (int*)alloc((size_t)Etot*4);
  __half*   attrC16 = (__half*)alloc((size_t)Etot*FF*2);
  float*    attrdot = (float*)alloc((size_t)5*Etot*2*4);
  __half2*  eaBuf   = (__half2*)alloc((size_t)Etot*4);
  __half*   wh      = (__half*)alloc((size_t)5*DD*HD*2);
  float*    c5      = (float*)alloc(5*34*4);

  int* counts = (int*)sbuf;                       // build-phase alias
  int* cursor = (int*)((char*)sbuf + 65536);      // build-phase alias

  const int ebl = (Etot + 255)/256;

  // CSR build (layer-invariant) + constants + W fp16 + attr precompute
  hipMemsetAsync(counts, 0, (size_t)N*4, stream);
  k_hist_prec<<<ebl+165, 256, 0, stream>>>(dst, counts, atts, edge_ws, edge_bs, weights,
                                           c5, wh, E, Etot, ebl);
  k_scan<<<1, 1024, 0, stream>>>(counts, starts, cursor, N, Etot);
  k_scatter<<<ebl, 256, 0, stream>>>(dst, cursor, eids, E, Etot);
  k_gather_csr<<<ebl, 256, 0, stream>>>(eids, src, dst, eattr, srcC, dstC, attrC16, E, Etot);
  k_attrdot<<<ebl, 256, 0, stream>>>(attrC16, c5, attrdot, Etot);

  const float* hin = x;
  for (int l = 0; l < 5; l++){
    const __half* Whl = wh + (size_t)l*DD*HD;
    const float* att = atts    + (size_t)l*HEADS*2*DD;
    const float* b   = biases  + (size_t)l*DD;
    const float* ew  = edge_ws + (size_t)l*HD*FF;
    const float* eb  = edge_bs + (size_t)l*HD;
    const float* c   = c5 + (size_t)l*34;
    const float* adL = attrdot + (size_t)l*Etot*2;
    float* hout = (l == 4) ? (float*)d_out : ((l & 1) ? hB : hA);
    int relu = (l < 4) ? 1 : 0;

    k_gemm_xw<<<(N+15)/16, 256, 0, stream>>>(hin, Whl, att, xwh, sbuf, N);
    k_ea<<<ebl, 256, 0, stream>>>(srcC, dstC, adL, sbuf, c, eaBuf, Etot);
    k_aggr2<<<N, 256, 0, stream>>>(starts, srcC, attrC16, eaBuf, xwh, ew, eb, b, hout, N, relu);

    hin = hout;
  }
}